// Round 1
// baseline (1742.884 us; speedup 1.0000x reference)
//
#include <hip/hip_runtime.h>

// TensorProductConvLayer — fp32 correctness-first fused implementation.
//
// Pipeline:
//   memset(agg, stats)                                  (capture-legal async memset)
//   K1  fc1:   h = relu(edge_attr @ fc1_w + fc1_b)      -> ws.h   [E,64]
//   K2  fused: per edge, w = h @ fc2_w + fc2_b computed on the fly from
//              LDS-resident weights (k-split across grid.y=2 for occupancy),
//              contracted immediately with TP coefficients, atomicAdd -> agg
//   K3a resid+stats: pre = agg + node_attr -> d_out, wave-reduced sums -> stats
//   K3b batchnorm apply in-place on d_out
//
// ws layout: [0, 81920000) h | [81920000, 85120000) agg | [85120000, +160) stats
// ws required: 85,120,160 bytes.

#define E_EDGES   320000
#define N_NODES_C 20000
#define NS_C      16
#define NV_C      8
#define D_C       40
#define F_C       64
#define WN_C      576
#define A0_C      0.20412414523193154f   // 1/sqrt(24)
#define RSQRT3_C  0.57735026918962576f   // 1/sqrt(3)

__device__ __forceinline__ float4 ld4(const float* p) {
  return *reinterpret_cast<const float4*>(p);
}
__device__ __forceinline__ void st4(float* p, float a, float b, float c, float d) {
  *reinterpret_cast<float4*>(p) = make_float4(a, b, c, d);
}

// ---------------------------------------------------------------- K1: fc1+relu
__global__ __launch_bounds__(256, 4) void fc1_kernel(
    const float* __restrict__ ea, const float* __restrict__ w,
    const float* __restrict__ b, float* __restrict__ h)
{
  __shared__ float ws[64 * 64];
  __shared__ float bs[64];
  const int tid = threadIdx.x;
#pragma unroll
  for (int i = 0; i < 4; ++i) {
    const int idx = (tid + i * 256) * 4;
    *reinterpret_cast<float4*>(&ws[idx]) = ld4(w + idx);
  }
  if (tid < 64) bs[tid] = b[tid];
  __syncthreads();

  const int e = blockIdx.x * 256 + tid;   // grid 1250*256 == 320000 exact
  float ar[64];
  const float* ep = ea + (size_t)e * 64;
#pragma unroll
  for (int i = 0; i < 16; ++i) {
    float4 v = ld4(ep + i * 4);
    ar[i * 4 + 0] = v.x; ar[i * 4 + 1] = v.y;
    ar[i * 4 + 2] = v.z; ar[i * 4 + 3] = v.w;
  }
  float* hp = h + (size_t)e * 64;
#pragma unroll 1
  for (int jb = 0; jb < 4; ++jb) {
    float acc[16];
#pragma unroll
    for (int j = 0; j < 16; ++j) acc[j] = bs[jb * 16 + j];
#pragma unroll
    for (int k = 0; k < 64; ++k) {
      const float hk = ar[k];
#pragma unroll
      for (int j4 = 0; j4 < 4; ++j4) {
        float4 wv = ld4(&ws[k * 64 + jb * 16 + j4 * 4]);
        acc[j4 * 4 + 0] += hk * wv.x;
        acc[j4 * 4 + 1] += hk * wv.y;
        acc[j4 * 4 + 2] += hk * wv.z;
        acc[j4 * 4 + 3] += hk * wv.w;
      }
    }
#pragma unroll
    for (int j4 = 0; j4 < 4; ++j4) {
      st4(hp + jb * 16 + j4 * 4,
          fmaxf(acc[j4 * 4 + 0], 0.f), fmaxf(acc[j4 * 4 + 1], 0.f),
          fmaxf(acc[j4 * 4 + 2], 0.f), fmaxf(acc[j4 * 4 + 3], 0.f));
    }
  }
}

// ------------------------------------------------------- K2: fused fc2 + TP
// grid = (625, 2): x = 512-edge tile, y = k-half (h[:,0:32] vs h[:,32:64]).
// LDS = 32x576 weight rows + 576 bias = 76032 B -> 2 blocks/CU.
__global__ __launch_bounds__(512, 4) void edge_kernel(
    const float* __restrict__ h, const float* __restrict__ w2g,
    const float* __restrict__ b2, const float* __restrict__ na,
    const float* __restrict__ sh, const int* __restrict__ ei,
    float* __restrict__ agg)
{
  extern __shared__ float lds[];
  const int tid = threadIdx.x;
  const int kh = blockIdx.y;

  const float4* wsrc = reinterpret_cast<const float4*>(w2g + kh * 32 * WN_C);
  for (int i = tid; i < (32 * WN_C) / 4; i += 512)
    reinterpret_cast<float4*>(lds)[i] = wsrc[i];
  for (int i = tid; i < WN_C; i += 512) lds[32 * WN_C + i] = b2[i];
  __syncthreads();

  const float bscale = (kh == 0) ? 1.f : 0.f;
  const float* __restrict__ lb = lds + 32 * WN_C;

  const int e = blockIdx.x * 512 + tid;   // 625*512 == 320000 exact
  const int src = ei[e];
  const int dst = ei[E_EDGES + e];
  const float4 shq = ld4(sh + (size_t)e * 4);
  const float shs = shq.x, shv0 = shq.y, shv1 = shq.z, shv2 = shq.w;
  const float* __restrict__ nas = na + (size_t)src * D_C;

  float hr[32];
  const float* hp = h + (size_t)e * 64 + kh * 32;
#pragma unroll
  for (int i = 0; i < 8; ++i) {
    float4 v = ld4(hp + i * 4);
    hr[i * 4 + 0] = v.x; hr[i * 4 + 1] = v.y;
    hr[i * 4 + 2] = v.z; hr[i * 4 + 3] = v.w;
  }

  float out0[16];
#pragma unroll
  for (int j = 0; j < 16; ++j) out0[j] = 0.f;

  // ---- w1 block: j = u*16+wo, u=0..15 -> out0[wo] += w*xs[u]*shs*a0
#pragma unroll 1
  for (int u = 0; u < 16; ++u) {
    float wa[16];
#pragma unroll
    for (int j4 = 0; j4 < 4; ++j4) {
      float4 bv = ld4(&lb[u * 16 + j4 * 4]);
      wa[j4 * 4 + 0] = bv.x * bscale; wa[j4 * 4 + 1] = bv.y * bscale;
      wa[j4 * 4 + 2] = bv.z * bscale; wa[j4 * 4 + 3] = bv.w * bscale;
    }
    const float* wl = lds + u * 16;
#pragma unroll
    for (int k = 0; k < 32; ++k) {
      const float hk = hr[k];
#pragma unroll
      for (int j4 = 0; j4 < 4; ++j4) {
        float4 wv = ld4(wl + k * WN_C + j4 * 4);
        wa[j4 * 4 + 0] += hk * wv.x;
        wa[j4 * 4 + 1] += hk * wv.y;
        wa[j4 * 4 + 2] += hk * wv.z;
        wa[j4 * 4 + 3] += hk * wv.w;
      }
    }
    const float c = nas[u] * shs * A0_C;
#pragma unroll
    for (int j = 0; j < 16; ++j) out0[j] += wa[j] * c;
  }

  // ---- w4 block: j = 448 + u*16+wo, u=0..7 -> out0[wo] += w*dot[u]*a0
#pragma unroll 1
  for (int u = 0; u < 8; ++u) {
    float wa[16];
#pragma unroll
    for (int j4 = 0; j4 < 4; ++j4) {
      float4 bv = ld4(&lb[448 + u * 16 + j4 * 4]);
      wa[j4 * 4 + 0] = bv.x * bscale; wa[j4 * 4 + 1] = bv.y * bscale;
      wa[j4 * 4 + 2] = bv.z * bscale; wa[j4 * 4 + 3] = bv.w * bscale;
    }
    const float* wl = lds + 448 + u * 16;
#pragma unroll
    for (int k = 0; k < 32; ++k) {
      const float hk = hr[k];
#pragma unroll
      for (int j4 = 0; j4 < 4; ++j4) {
        float4 wv = ld4(wl + k * WN_C + j4 * 4);
        wa[j4 * 4 + 0] += hk * wv.x;
        wa[j4 * 4 + 1] += hk * wv.y;
        wa[j4 * 4 + 2] += hk * wv.z;
        wa[j4 * 4 + 3] += hk * wv.w;
      }
    }
    const float xv0 = nas[16 + u * 3 + 0];
    const float xv1 = nas[16 + u * 3 + 1];
    const float xv2 = nas[16 + u * 3 + 2];
    const float c = (xv0 * shv0 + xv1 * shv1 + xv2 * shv2) * (RSQRT3_C * A0_C);
#pragma unroll
    for (int j = 0; j < 16; ++j) out0[j] += wa[j] * c;
  }

  float* ap = agg + (size_t)dst * D_C;
#pragma unroll
  for (int j = 0; j < 16; ++j) atomicAdd(ap + j, out0[j]);

  float out1[24];
#pragma unroll
  for (int j = 0; j < 24; ++j) out1[j] = 0.f;

  // ---- w2 block: j = 256 + u*8+wo, u=0..15 -> out1[wo][m] += w*xs[u]*shv[m]*a1
#pragma unroll 1
  for (int u = 0; u < 16; ++u) {
    float wa[8];
    {
      float4 b0 = ld4(&lb[256 + u * 8 + 0]);
      float4 b1 = ld4(&lb[256 + u * 8 + 4]);
      wa[0] = b0.x * bscale; wa[1] = b0.y * bscale;
      wa[2] = b0.z * bscale; wa[3] = b0.w * bscale;
      wa[4] = b1.x * bscale; wa[5] = b1.y * bscale;
      wa[6] = b1.z * bscale; wa[7] = b1.w * bscale;
    }
    const float* wl = lds + 256 + u * 8;
#pragma unroll
    for (int k = 0; k < 32; ++k) {
      const float hk = hr[k];
      float4 w0 = ld4(wl + k * WN_C + 0);
      float4 w1 = ld4(wl + k * WN_C + 4);
      wa[0] += hk * w0.x; wa[1] += hk * w0.y;
      wa[2] += hk * w0.z; wa[3] += hk * w0.w;
      wa[4] += hk * w1.x; wa[5] += hk * w1.y;
      wa[6] += hk * w1.z; wa[7] += hk * w1.w;
    }
    const float t = nas[u] * A0_C;   // a1 == a0
    const float c0 = t * shv0, c1 = t * shv1, c2 = t * shv2;
#pragma unroll
    for (int j = 0; j < 8; ++j) {
      out1[j * 3 + 0] += wa[j] * c0;
      out1[j * 3 + 1] += wa[j] * c1;
      out1[j * 3 + 2] += wa[j] * c2;
    }
  }

  // ---- w3 block: j = 384 + u*8+wo, u=0..7 -> out1[wo][m] += w*xv[u][m]*shs*a1
#pragma unroll 1
  for (int u = 0; u < 8; ++u) {
    float wa[8];
    {
      float4 b0 = ld4(&lb[384 + u * 8 + 0]);
      float4 b1 = ld4(&lb[384 + u * 8 + 4]);
      wa[0] = b0.x * bscale; wa[1] = b0.y * bscale;
      wa[2] = b0.z * bscale; wa[3] = b0.w * bscale;
      wa[4] = b1.x * bscale; wa[5] = b1.y * bscale;
      wa[6] = b1.z * bscale; wa[7] = b1.w * bscale;
    }
    const float* wl = lds + 384 + u * 8;
#pragma unroll
    for (int k = 0; k < 32; ++k) {
      const float hk = hr[k];
      float4 w0 = ld4(wl + k * WN_C + 0);
      float4 w1 = ld4(wl + k * WN_C + 4);
      wa[0] += hk * w0.x; wa[1] += hk * w0.y;
      wa[2] += hk * w0.z; wa[3] += hk * w0.w;
      wa[4] += hk * w1.x; wa[5] += hk * w1.y;
      wa[6] += hk * w1.z; wa[7] += hk * w1.w;
    }
    const float s = shs * A0_C;
    const float c0 = nas[16 + u * 3 + 0] * s;
    const float c1 = nas[16 + u * 3 + 1] * s;
    const float c2 = nas[16 + u * 3 + 2] * s;
#pragma unroll
    for (int j = 0; j < 8; ++j) {
      out1[j * 3 + 0] += wa[j] * c0;
      out1[j * 3 + 1] += wa[j] * c1;
      out1[j * 3 + 2] += wa[j] * c2;
    }
  }

#pragma unroll
  for (int j = 0; j < 24; ++j) atomicAdd(ap + 16 + j, out1[j]);
}

// -------------------------------------------- K3a: residual add + BN statistics
__global__ __launch_bounds__(256) void resid_stats_kernel(
    const float* __restrict__ agg, const float* __restrict__ na,
    float* __restrict__ outp, float* __restrict__ stats)
{
  const int n = blockIdx.x * 256 + threadIdx.x;
  float v[40];
  if (n < N_NODES_C) {
    const float* ap = agg + (size_t)n * D_C;
    const float* np = na + (size_t)n * D_C;
#pragma unroll
    for (int i = 0; i < 10; ++i) {
      float4 a = ld4(ap + i * 4);
      float4 b = ld4(np + i * 4);
      v[i * 4 + 0] = a.x + b.x; v[i * 4 + 1] = a.y + b.y;
      v[i * 4 + 2] = a.z + b.z; v[i * 4 + 3] = a.w + b.w;
    }
    float* op = outp + (size_t)n * D_C;
#pragma unroll
    for (int i = 0; i < 10; ++i)
      st4(op + i * 4, v[i * 4 + 0], v[i * 4 + 1], v[i * 4 + 2], v[i * 4 + 3]);
  } else {
#pragma unroll
    for (int i = 0; i < 40; ++i) v[i] = 0.f;
  }

  // per-wave reduction of 40 statistics: sum_s[16], sumsq_s[16], sumsq_v[8]
  float red[40];
#pragma unroll
  for (int c = 0; c < 16; ++c) { red[c] = v[c]; red[16 + c] = v[c] * v[c]; }
#pragma unroll
  for (int u = 0; u < 8; ++u) {
    const float a = v[16 + u * 3 + 0], b = v[16 + u * 3 + 1], c = v[16 + u * 3 + 2];
    red[32 + u] = a * a + b * b + c * c;
  }
#pragma unroll
  for (int i = 0; i < 40; ++i) {
    float x = red[i];
#pragma unroll
    for (int off = 32; off > 0; off >>= 1) x += __shfl_xor(x, off, 64);
    red[i] = x;
  }
  if ((threadIdx.x & 63) == 0) {
#pragma unroll
    for (int i = 0; i < 40; ++i) atomicAdd(stats + i, red[i]);
  }
}

// ------------------------------------------------------------ K3b: BN apply
__global__ __launch_bounds__(256) void bn_apply_kernel(
    float* __restrict__ outp, const float* __restrict__ stats,
    const float* __restrict__ gs, const float* __restrict__ bsv,
    const float* __restrict__ gv)
{
  __shared__ float A[16], B[16], AV[8];
  const int tid = threadIdx.x;
  if (tid < 16) {
    const float s = stats[tid], q = stats[16 + tid];
    const float mu = s * (1.f / 20000.f);
    const float var = q * (1.f / 20000.f) - mu * mu;
    const float a = rsqrtf(var + 1e-5f) * gs[tid];
    A[tid] = a;
    B[tid] = bsv[tid] - mu * a;
  } else if (tid < 24) {
    const int u = tid - 16;
    const float vn = stats[32 + u] * (1.f / (20000.f * 3.f));
    AV[u] = rsqrtf(vn + 1e-5f) * gv[u];
  }
  __syncthreads();

  const int n = blockIdx.x * 256 + tid;
  if (n < N_NODES_C) {
    float* op = outp + (size_t)n * D_C;
    float v[40];
#pragma unroll
    for (int i = 0; i < 10; ++i) {
      float4 t = ld4(op + i * 4);
      v[i * 4 + 0] = t.x; v[i * 4 + 1] = t.y; v[i * 4 + 2] = t.z; v[i * 4 + 3] = t.w;
    }
#pragma unroll
    for (int c = 0; c < 16; ++c) v[c] = v[c] * A[c] + B[c];
#pragma unroll
    for (int u = 0; u < 8; ++u) {
      const float a = AV[u];
      v[16 + u * 3 + 0] *= a; v[16 + u * 3 + 1] *= a; v[16 + u * 3 + 2] *= a;
    }
#pragma unroll
    for (int i = 0; i < 10; ++i)
      st4(op + i * 4, v[i * 4 + 0], v[i * 4 + 1], v[i * 4 + 2], v[i * 4 + 3]);
  }
}

// ---------------------------------------------------------------- launcher
extern "C" void kernel_launch(void* const* d_in, const int* in_sizes, int n_in,
                              void* d_out, int out_size, void* d_ws, size_t ws_size,
                              hipStream_t stream) {
  const float* node_attr = (const float*)d_in[0];
  const float* edge_attr = (const float*)d_in[1];
  const float* edge_sh   = (const float*)d_in[2];
  const float* fc1_w     = (const float*)d_in[3];
  const float* fc1_b     = (const float*)d_in[4];
  const float* fc2_w     = (const float*)d_in[5];
  const float* fc2_b     = (const float*)d_in[6];
  const float* gs        = (const float*)d_in[7];
  const float* bs        = (const float*)d_in[8];
  const float* gv        = (const float*)d_in[9];
  const int*   ei        = (const int*)d_in[10];
  float* out = (float*)d_out;

  char* ws = (char*)d_ws;
  float* h     = (float*)(ws);                          // 320000*64*4 = 81,920,000
  float* agg   = (float*)(ws + 81920000);               // 20000*40*4  =  3,200,000
  float* stats = (float*)(ws + 81920000 + 3200000);     // 40*4        =        160

  // zero agg + stats (harness poisons ws with 0xAA before every timed call)
  hipMemsetAsync(agg, 0, 3200000 + 160, stream);

  fc1_kernel<<<1250, 256, 0, stream>>>(edge_attr, fc1_w, fc1_b, h);

  // 76,032 B dynamic LDS > 64 KB default -> opt in (idempotent, capture-safe)
  hipFuncSetAttribute((const void*)edge_kernel,
                      hipFuncAttributeMaxDynamicSharedMemorySize, 76032);
  edge_kernel<<<dim3(625, 2), 512, 76032, stream>>>(
      h, fc2_w, fc2_b, node_attr, edge_sh, ei, agg);

  resid_stats_kernel<<<79, 256, 0, stream>>>(agg, node_attr, out, stats);
  bn_apply_kernel<<<79, 256, 0, stream>>>(out, stats, gs, bs, gv);
}

// Round 3
// 1499.608 us; speedup vs baseline: 1.1622x; 1.1622x over previous
//
#include <hip/hip_runtime.h>

// TensorProductConvLayer — round 3 (== round 2 resubmit; R2 bench was an
// infra GPUAcquisitionTimeout, kernel never ran).
//
// R1 post-mortem: LDS-broadcast weight reads bound the edge kernel
// (VALUBusy 12.5%, ~4608 ds_read_b128/wave at ~12cyc/instr per CU).
// Weights are wave-uniform -> load via scalar (SMEM) pipe into SGPRs and
// feed v_fma_f32 with an SGPR operand: 16 FMAs per 64B s_load.
// k-halves now iterate INSIDE the thread (weights partitioned by k, TP
// coefficients linear over k-partials) -> atomics per edge halved vs R1.
//
// ws layout: [0, 81920000) h | [81920000, 85120000) agg | [85120000, +160) stats

#define E_EDGES   320000
#define N_NODES_C 20000
#define NS_C      16
#define NV_C      8
#define D_C       40
#define F_C       64
#define WN_C      576
#define A0_C      0.20412414523193154f   // 1/sqrt(24)
#define RSQRT3_C  0.57735026918962576f   // 1/sqrt(3)

__device__ __forceinline__ float4 ld4(const float* p) {
  return *reinterpret_cast<const float4*>(p);
}
__device__ __forceinline__ void st4(float* p, float a, float b, float c, float d) {
  *reinterpret_cast<float4*>(p) = make_float4(a, b, c, d);
}

// ---------------------------------------------------------------- K1: fc1+relu
// Per-thread edge; weights via uniform scalar loads (SMEM), no LDS.
__global__ __launch_bounds__(256, 4) void fc1_kernel(
    const float* __restrict__ ea, const float* __restrict__ w,
    const float* __restrict__ b, float* __restrict__ h)
{
  const int e = blockIdx.x * 256 + threadIdx.x;   // 1250*256 == 320000 exact
  float ar[64];
  const float* ep = ea + (size_t)e * 64;
#pragma unroll
  for (int i = 0; i < 16; ++i) {
    float4 v = ld4(ep + i * 4);
    ar[i * 4 + 0] = v.x; ar[i * 4 + 1] = v.y;
    ar[i * 4 + 2] = v.z; ar[i * 4 + 3] = v.w;
  }
  float* hp = h + (size_t)e * 64;
#pragma unroll 1
  for (int jb = 0; jb < 4; ++jb) {
    float acc[16];
#pragma unroll
    for (int j = 0; j < 16; ++j) acc[j] = b[jb * 16 + j];        // uniform
#pragma unroll 4
    for (int k = 0; k < 64; ++k) {
      const float* __restrict__ wr = w + k * 64 + jb * 16;        // uniform row
      const float hk = ar[k];
#pragma unroll
      for (int j = 0; j < 16; ++j) acc[j] += hk * wr[j];          // s_load + v_fma(sgpr)
    }
#pragma unroll
    for (int j4 = 0; j4 < 4; ++j4) {
      st4(hp + jb * 16 + j4 * 4,
          fmaxf(acc[j4 * 4 + 0], 0.f), fmaxf(acc[j4 * 4 + 1], 0.f),
          fmaxf(acc[j4 * 4 + 2], 0.f), fmaxf(acc[j4 * 4 + 3], 0.f));
    }
  }
}

// ------------------------------------------------------- K2: fused fc2 + TP
// One thread per edge, full K=64 handled as two in-thread k-halves.
// All fc2 weights/bias read as wave-uniform scalar loads. No LDS.
__global__ __launch_bounds__(256, 4) void edge_kernel(
    const float* __restrict__ h, const float* __restrict__ w2g,
    const float* __restrict__ b2, const float* __restrict__ na,
    const float* __restrict__ sh, const int* __restrict__ ei,
    float* __restrict__ agg)
{
  const int e = blockIdx.x * 256 + threadIdx.x;   // 1250*256 == 320000 exact
  const int src = ei[e];
  const int dst = ei[E_EDGES + e];
  const float4 shq = ld4(sh + (size_t)e * 4);
  const float shs = shq.x, shv0 = shq.y, shv1 = shq.z, shv2 = shq.w;
  const float* __restrict__ nas = na + (size_t)src * D_C;

  float out0[16];
  float out1[24];
#pragma unroll
  for (int j = 0; j < 16; ++j) out0[j] = 0.f;
#pragma unroll
  for (int j = 0; j < 24; ++j) out1[j] = 0.f;

#pragma unroll 1
  for (int kh = 0; kh < 2; ++kh) {
    const float bsc = (kh == 0) ? 1.f : 0.f;      // bias applied once
    const float* __restrict__ wb = w2g + (size_t)kh * 32 * WN_C;

    float hr[32];
    const float* hp = h + (size_t)e * 64 + kh * 32;
#pragma unroll
    for (int i = 0; i < 8; ++i) {
      float4 v = ld4(hp + i * 4);
      hr[i * 4 + 0] = v.x; hr[i * 4 + 1] = v.y;
      hr[i * 4 + 2] = v.z; hr[i * 4 + 3] = v.w;
    }

    // ---- w1 block: cols u*16+wo, u=0..15 -> out0[wo] += w*xs[u]*shs*a0
#pragma unroll 1
    for (int u = 0; u < 16; ++u) {
      const float c = nas[u] * shs * A0_C;        // per-lane gather, hides under k-loop
      float wa[16];
#pragma unroll
      for (int j = 0; j < 16; ++j) wa[j] = b2[u * 16 + j] * bsc;  // uniform
#pragma unroll 4
      for (int k = 0; k < 32; ++k) {
        const float* __restrict__ wr = wb + (size_t)k * WN_C + u * 16;
        const float hk = hr[k];
#pragma unroll
        for (int j = 0; j < 16; ++j) wa[j] += hk * wr[j];
      }
#pragma unroll
      for (int j = 0; j < 16; ++j) out0[j] += wa[j] * c;
    }

    // ---- w4 block: cols 448+u*16+wo, u=0..7 -> out0[wo] += w*dot[u]*a0
#pragma unroll 1
    for (int u = 0; u < 8; ++u) {
      const float xv0 = nas[16 + u * 3 + 0];
      const float xv1 = nas[16 + u * 3 + 1];
      const float xv2 = nas[16 + u * 3 + 2];
      const float c = (xv0 * shv0 + xv1 * shv1 + xv2 * shv2) * (RSQRT3_C * A0_C);
      float wa[16];
#pragma unroll
      for (int j = 0; j < 16; ++j) wa[j] = b2[448 + u * 16 + j] * bsc;
#pragma unroll 4
      for (int k = 0; k < 32; ++k) {
        const float* __restrict__ wr = wb + (size_t)k * WN_C + 448 + u * 16;
        const float hk = hr[k];
#pragma unroll
        for (int j = 0; j < 16; ++j) wa[j] += hk * wr[j];
      }
#pragma unroll
      for (int j = 0; j < 16; ++j) out0[j] += wa[j] * c;
    }

    // ---- w2 block: cols 256+u*8+wo, u=0..15 -> out1[wo][m] += w*xs[u]*shv[m]*a1
#pragma unroll 1
    for (int u = 0; u < 16; ++u) {
      const float t = nas[u] * A0_C;              // a1 == a0
      float wa[8];
#pragma unroll
      for (int j = 0; j < 8; ++j) wa[j] = b2[256 + u * 8 + j] * bsc;
#pragma unroll 4
      for (int k = 0; k < 32; ++k) {
        const float* __restrict__ wr = wb + (size_t)k * WN_C + 256 + u * 8;
        const float hk = hr[k];
#pragma unroll
        for (int j = 0; j < 8; ++j) wa[j] += hk * wr[j];
      }
      const float c0 = t * shv0, c1 = t * shv1, c2 = t * shv2;
#pragma unroll
      for (int j = 0; j < 8; ++j) {
        out1[j * 3 + 0] += wa[j] * c0;
        out1[j * 3 + 1] += wa[j] * c1;
        out1[j * 3 + 2] += wa[j] * c2;
      }
    }

    // ---- w3 block: cols 384+u*8+wo, u=0..7 -> out1[wo][m] += w*xv[u][m]*shs*a1
#pragma unroll 1
    for (int u = 0; u < 8; ++u) {
      const float s = shs * A0_C;
      const float c0 = nas[16 + u * 3 + 0] * s;
      const float c1 = nas[16 + u * 3 + 1] * s;
      const float c2 = nas[16 + u * 3 + 2] * s;
      float wa[8];
#pragma unroll
      for (int j = 0; j < 8; ++j) wa[j] = b2[384 + u * 8 + j] * bsc;
#pragma unroll 4
      for (int k = 0; k < 32; ++k) {
        const float* __restrict__ wr = wb + (size_t)k * WN_C + 384 + u * 8;
        const float hk = hr[k];
#pragma unroll
        for (int j = 0; j < 8; ++j) wa[j] += hk * wr[j];
      }
#pragma unroll
      for (int j = 0; j < 8; ++j) {
        out1[j * 3 + 0] += wa[j] * c0;
        out1[j * 3 + 1] += wa[j] * c1;
        out1[j * 3 + 2] += wa[j] * c2;
      }
    }
  }

  float* ap = agg + (size_t)dst * D_C;
#pragma unroll
  for (int j = 0; j < 16; ++j) atomicAdd(ap + j, out0[j]);
#pragma unroll
  for (int j = 0; j < 24; ++j) atomicAdd(ap + 16 + j, out1[j]);
}

// -------------------------------------------- K3a: residual add + BN statistics
__global__ __launch_bounds__(256) void resid_stats_kernel(
    const float* __restrict__ agg, const float* __restrict__ na,
    float* __restrict__ outp, float* __restrict__ stats)
{
  const int n = blockIdx.x * 256 + threadIdx.x;
  float v[40];
  if (n < N_NODES_C) {
    const float* ap = agg + (size_t)n * D_C;
    const float* np = na + (size_t)n * D_C;
#pragma unroll
    for (int i = 0; i < 10; ++i) {
      float4 a = ld4(ap + i * 4);
      float4 b = ld4(np + i * 4);
      v[i * 4 + 0] = a.x + b.x; v[i * 4 + 1] = a.y + b.y;
      v[i * 4 + 2] = a.z + b.z; v[i * 4 + 3] = a.w + b.w;
    }
    float* op = outp + (size_t)n * D_C;
#pragma unroll
    for (int i = 0; i < 10; ++i)
      st4(op + i * 4, v[i * 4 + 0], v[i * 4 + 1], v[i * 4 + 2], v[i * 4 + 3]);
  } else {
#pragma unroll
    for (int i = 0; i < 40; ++i) v[i] = 0.f;
  }

  float red[40];
#pragma unroll
  for (int c = 0; c < 16; ++c) { red[c] = v[c]; red[16 + c] = v[c] * v[c]; }
#pragma unroll
  for (int u = 0; u < 8; ++u) {
    const float a = v[16 + u * 3 + 0], b = v[16 + u * 3 + 1], c = v[16 + u * 3 + 2];
    red[32 + u] = a * a + b * b + c * c;
  }
#pragma unroll
  for (int i = 0; i < 40; ++i) {
    float x = red[i];
#pragma unroll
    for (int off = 32; off > 0; off >>= 1) x += __shfl_xor(x, off, 64);
    red[i] = x;
  }
  if ((threadIdx.x & 63) == 0) {
#pragma unroll
    for (int i = 0; i < 40; ++i) atomicAdd(stats + i, red[i]);
  }
}

// ------------------------------------------------------------ K3b: BN apply
__global__ __launch_bounds__(256) void bn_apply_kernel(
    float* __restrict__ outp, const float* __restrict__ stats,
    const float* __restrict__ gs, const float* __restrict__ bsv,
    const float* __restrict__ gv)
{
  __shared__ float A[16], B[16], AV[8];
  const int tid = threadIdx.x;
  if (tid < 16) {
    const float s = stats[tid], q = stats[16 + tid];
    const float mu = s * (1.f / 20000.f);
    const float var = q * (1.f / 20000.f) - mu * mu;
    const float a = rsqrtf(var + 1e-5f) * gs[tid];
    A[tid] = a;
    B[tid] = bsv[tid] - mu * a;
  } else if (tid < 24) {
    const int u = tid - 16;
    const float vn = stats[32 + u] * (1.f / (20000.f * 3.f));
    AV[u] = rsqrtf(vn + 1e-5f) * gv[u];
  }
  __syncthreads();

  const int n = blockIdx.x * 256 + tid;
  if (n < N_NODES_C) {
    float* op = outp + (size_t)n * D_C;
    float v[40];
#pragma unroll
    for (int i = 0; i < 10; ++i) {
      float4 t = ld4(op + i * 4);
      v[i * 4 + 0] = t.x; v[i * 4 + 1] = t.y; v[i * 4 + 2] = t.z; v[i * 4 + 3] = t.w;
    }
#pragma unroll
    for (int c = 0; c < 16; ++c) v[c] = v[c] * A[c] + B[c];
#pragma unroll
    for (int u = 0; u < 8; ++u) {
      const float a = AV[u];
      v[16 + u * 3 + 0] *= a; v[16 + u * 3 + 1] *= a; v[16 + u * 3 + 2] *= a;
    }
#pragma unroll
    for (int i = 0; i < 10; ++i)
      st4(op + i * 4, v[i * 4 + 0], v[i * 4 + 1], v[i * 4 + 2], v[i * 4 + 3]);
  }
}

// ---------------------------------------------------------------- launcher
extern "C" void kernel_launch(void* const* d_in, const int* in_sizes, int n_in,
                              void* d_out, int out_size, void* d_ws, size_t ws_size,
                              hipStream_t stream) {
  const float* node_attr = (const float*)d_in[0];
  const float* edge_attr = (const float*)d_in[1];
  const float* edge_sh   = (const float*)d_in[2];
  const float* fc1_w     = (const float*)d_in[3];
  const float* fc1_b     = (const float*)d_in[4];
  const float* fc2_w     = (const float*)d_in[5];
  const float* fc2_b     = (const float*)d_in[6];
  const float* gs        = (const float*)d_in[7];
  const float* bs        = (const float*)d_in[8];
  const float* gv        = (const float*)d_in[9];
  const int*   ei        = (const int*)d_in[10];
  float* out = (float*)d_out;

  char* ws = (char*)d_ws;
  float* h     = (float*)(ws);                          // 320000*64*4 = 81,920,000
  float* agg   = (float*)(ws + 81920000);               // 20000*40*4  =  3,200,000
  float* stats = (float*)(ws + 81920000 + 3200000);     // 40*4        =        160

  hipMemsetAsync(agg, 0, 3200000 + 160, stream);

  fc1_kernel<<<1250, 256, 0, stream>>>(edge_attr, fc1_w, fc1_b, h);
  edge_kernel<<<1250, 256, 0, stream>>>(h, fc2_w, fc2_b, node_attr, edge_sh, ei, agg);
  resid_stats_kernel<<<79, 256, 0, stream>>>(agg, node_attr, out, stats);
  bn_apply_kernel<<<79, 256, 0, stream>>>(out, stats, gs, bs, gv);
}

// Round 8
// 450.703 us; speedup vs baseline: 3.8670x; 3.3273x over previous
//
#include <hip/hip_runtime.h>
#include <stdint.h>

// TensorProductConvLayer — round 8 (== round 4 resubmit; R4-R7 benches were
// infra GPUAcquisitionTimeouts, kernel never ran).
//
// R1: LDS-broadcast weight feed -> LDS-pipe-bound (1471 us, VALUBusy 12.5%).
// R3: SGPR/SMEM weight feed -> scalar-cache-thrash latency-bound (1190 us,
//     VALUBusy 16.5%, SGPR=96 proves scalarization happened).
// Both: one shared feed pipe per CU vs 4 VALU SIMDs. Fix: matrix pipe.
//
// Precision: A and B are split h = hi + lo (bf16 RNE pair, exact to ~2^-16):
//   A' = [h_hi | h_lo | h_hi]  (K=192),  B' = [W_hi ; W_hi ; W_lo]
// => h_hi*W_hi + h_lo*W_hi + h_hi*W_lo  (drops only lo*lo ~ 2^-16 rel).
//
// Layouts (m89/m91-verified conventions):
//   A-frag: row = lane&15, k = (lane>>4)*8 + t
//   B-frag: col = lane&15, k = (lane>>4)*8 + t
//   C/D   : col = lane&15, row = (lane>>4)*4 + reg
//
// ws: [0, 81.92MB) h2 (E x 64 dwords, word = hi|lo<<16) | agg 3.2MB | stats 160B
// Bpk (245,760 B packed B-fragments) lives in d_out (3.2MB), which is only
// written by K3a AFTER the edge kernel consumed Bpk (stream-ordered).

#define E_EDGES   320000
#define N_NODES_C 20000
#define D_C       40
#define A0_C      0.20412414523193154f   // 1/sqrt(24)
#define RSQRT3_C  0.57735026918962576f   // 1/sqrt(3)

typedef __attribute__((ext_vector_type(8))) short        bf16x8;
typedef __attribute__((ext_vector_type(4))) float        f32x4;
typedef __attribute__((ext_vector_type(4))) unsigned int u32x4;
typedef __attribute__((ext_vector_type(4))) int          i32x4;

__device__ __forceinline__ uint32_t rne16(uint32_t u) {
  return (u + 0x7fffu + ((u >> 16) & 1u)) >> 16;   // bf16 RNE, low 16 bits valid
}
__device__ __forceinline__ float4 ld4(const float* p) {
  return *reinterpret_cast<const float4*>(p);
}
__device__ __forceinline__ void st4(float* p, float a, float b, float c, float d) {
  *reinterpret_cast<float4*>(p) = make_float4(a, b, c, d);
}

// jp (processing order) -> original 16-col tile index. Phase A: w1 (jp 0..15),
// w4 (16..23); Phase B: w2 (24..31); Phase C: w3 (32..35).
__device__ __forceinline__ int cjp_map(int jp) {
  return jp < 16 ? jp : (jp < 24 ? jp + 12 : jp - 8);
}

// ---------------------------------------------------------------- B-pack
// Builds MFMA B-fragments for fc2 (frags 0..215: jp*6+s) and fc1 (216..239:
// nt*6+s). s in {0,1}: W_hi rows (s&1)*32..; {2,3}: W_hi again; {4,5}: W_lo.
__global__ __launch_bounds__(256) void pack_kernel(
    const float* __restrict__ w2, const float* __restrict__ w1f,
    uint32_t* __restrict__ bpk)
{
  const int tid = blockIdx.x * 256 + threadIdx.x;   // 240*256 = 61440 dwords
  const int frag = tid >> 8;
  const int d    = tid & 255;
  const int lane = d >> 2, q = d & 3;
  const float* W; int stride, col, s;
  if (frag < 216) {
    const int jp = frag / 6; s = frag % 6;
    col = cjp_map(jp) * 16 + (lane & 15); W = w2; stride = 576;
  } else {
    const int f1 = frag - 216; const int nt = f1 / 6; s = f1 % 6;
    col = nt * 16 + (lane & 15); W = w1f; stride = 64;
  }
  uint32_t out = 0;
#pragma unroll
  for (int h = 0; h < 2; ++h) {
    const int t = q * 2 + h;
    const int kk = (lane >> 4) * 8 + t;          // frag element -> k within 32
    const int krow = (s & 1) * 32 + kk;
    const float v = W[krow * stride + col];
    const uint32_t u = __float_as_uint(v);
    const uint32_t hb = rne16(u);
    uint32_t b16;
    if (s < 4) b16 = hb & 0xffffu;
    else {
      const float lo = v - __uint_as_float(hb << 16);
      b16 = rne16(__float_as_uint(lo)) & 0xffffu;
    }
    out |= b16 << (16 * h);
  }
  bpk[tid] = out;
}

// ---------------------------------------------------------------- K1: fc1 MFMA
// Wave = 64 edges. A-frags built on the fly from fp32 edge_attr (hi/lo split).
// Output h2[e][64 words], word c = hi(h[c]) | lo(h[c])<<16, h = relu(ea@W1+b1).
__global__ __launch_bounds__(256, 2) void fc1_mfma_kernel(
    const float* __restrict__ ea, const uint32_t* __restrict__ bpk,
    const float* __restrict__ b1, uint32_t* __restrict__ h2g)
{
  const int tid = threadIdx.x;
  const int w = tid >> 6, lane = tid & 63;
  const int n = lane & 15, g = lane >> 4;
  const int rowB = blockIdx.x * 256 + w * 64;

  bf16x8 Ahi[4][2], Alo[4][2];
#pragma unroll
  for (int mt = 0; mt < 4; ++mt) {
    const int row = rowB + mt * 16 + n;
    const float4* epv = reinterpret_cast<const float4*>(ea + (size_t)row * 64);
#pragma unroll
    for (int s = 0; s < 2; ++s) {
      const float4 fa = epv[s * 8 + g * 2];
      const float4 fb = epv[s * 8 + g * 2 + 1];
      float f[8] = {fa.x, fa.y, fa.z, fa.w, fb.x, fb.y, fb.z, fb.w};
      uint32_t hw[4], lw[4];
#pragma unroll
      for (int j = 0; j < 4; ++j) {
        const uint32_t u0 = __float_as_uint(f[2 * j]);
        const uint32_t u1 = __float_as_uint(f[2 * j + 1]);
        const uint32_t h0 = rne16(u0), h1 = rne16(u1);
        const float l0 = f[2 * j]     - __uint_as_float(h0 << 16);
        const float l1 = f[2 * j + 1] - __uint_as_float(h1 << 16);
        hw[j] = (h0 & 0xffffu) | (h1 << 16);
        lw[j] = (rne16(__float_as_uint(l0)) & 0xffffu) |
                (rne16(__float_as_uint(l1)) << 16);
      }
      u32x4 hv = {hw[0], hw[1], hw[2], hw[3]};
      u32x4 lv = {lw[0], lw[1], lw[2], lw[3]};
      Ahi[mt][s] = __builtin_bit_cast(bf16x8, hv);
      Alo[mt][s] = __builtin_bit_cast(bf16x8, lv);
    }
  }

  const u32x4* bp4 = reinterpret_cast<const u32x4*>(bpk);
#pragma unroll 1
  for (int nt = 0; nt < 4; ++nt) {
    u32x4 bfr[6];
#pragma unroll
    for (int s = 0; s < 6; ++s) bfr[s] = bp4[(216 + nt * 6 + s) * 64 + lane];
    f32x4 acc[4];
#pragma unroll
    for (int mt = 0; mt < 4; ++mt) acc[mt] = (f32x4)(0.0f);
#pragma unroll
    for (int s = 0; s < 6; ++s) {
      const bf16x8 B = __builtin_bit_cast(bf16x8, bfr[s]);
#pragma unroll
      for (int mt = 0; mt < 4; ++mt) {
        const bf16x8 A = (s < 2) ? Ahi[mt][s] : (s < 4 ? Alo[mt][s - 2] : Ahi[mt][s - 4]);
        acc[mt] = __builtin_amdgcn_mfma_f32_16x16x32_bf16(A, B, acc[mt], 0, 0, 0);
      }
    }
    const float bv = b1[nt * 16 + n];
#pragma unroll
    for (int mt = 0; mt < 4; ++mt) {
#pragma unroll
      for (int r = 0; r < 4; ++r) {
        const float v = fmaxf(acc[mt][r] + bv, 0.0f);
        const uint32_t hb = rne16(__float_as_uint(v));
        const float lo = v - __uint_as_float(hb << 16);
        const uint32_t lb = rne16(__float_as_uint(lo)) & 0xffffu;
        const int row = rowB + mt * 16 + g * 4 + r;       // C layout rows
        h2g[(size_t)row * 64 + nt * 16 + n] = (hb & 0xffffu) | (lb << 16);
      }
    }
  }
}

// ---------------------------------------------------------------- K2: fc2+TP
// Wave = 64 edges; full 576 cols looped as 36 16-col tiles (jp order), each
// tile's K=192 accumulated then immediately contracted with TP coefficients
// (lane-local: lane holds col n=lane&15, rows (lane>>4)*4+reg per m-subtile).
__global__ __launch_bounds__(256, 2) void edge_mfma_kernel(
    const uint32_t* __restrict__ h2g, const uint32_t* __restrict__ bpk,
    const float* __restrict__ b2, const float* __restrict__ na,
    const float* __restrict__ sh, const int* __restrict__ ei,
    float* __restrict__ agg)
{
  __shared__ __align__(16) float xsT[4][16][64];
  __shared__ __align__(16) float dtT[4][8][64];
  __shared__ __align__(16) float xvT[4][8][3][64];
  __shared__ __align__(16) float shsT[4][64];
  __shared__ __align__(16) float shvT[4][3][64];
  __shared__ __align__(16) int   dstT[4][64];
  __shared__ float b2s[576];

  const int tid = threadIdx.x;
  const int w = tid >> 6, lane = tid & 63;
  const int n = lane & 15, g = lane >> 4;
  const int eBlock = blockIdx.x * 256;

  // ---- stage per-edge coefficients (transposed for b128 broadcast reads)
  {
    const int e = eBlock + tid;
    const int src = ei[e];
    dstT[w][lane] = ei[E_EDGES + e];
    const float4 shq = ld4(sh + (size_t)e * 4);
    shsT[w][lane] = shq.x;
    shvT[w][0][lane] = shq.y; shvT[w][1][lane] = shq.z; shvT[w][2][lane] = shq.w;
    const float* nas = na + (size_t)src * D_C;
    float x[40];
#pragma unroll
    for (int i = 0; i < 10; ++i) {
      const float4 v = ld4(nas + i * 4);
      x[i * 4] = v.x; x[i * 4 + 1] = v.y; x[i * 4 + 2] = v.z; x[i * 4 + 3] = v.w;
    }
#pragma unroll
    for (int u = 0; u < 16; ++u) xsT[w][u][lane] = x[u];
#pragma unroll
    for (int u = 0; u < 8; ++u) {
      const float a = x[16 + u * 3], b = x[16 + u * 3 + 1], c = x[16 + u * 3 + 2];
      xvT[w][u][0][lane] = a; xvT[w][u][1][lane] = b; xvT[w][u][2][lane] = c;
      dtT[w][u][lane] = (a * shq.y + b * shq.z + c * shq.w) * RSQRT3_C;
    }
    if (tid < 144)
      reinterpret_cast<float4*>(b2s)[tid] = reinterpret_cast<const float4*>(b2)[tid];
  }
  __syncthreads();

  // ---- A fragments (read h2 once; hi-frags reused for ks 4,5)
  bf16x8 Ahi[4][2], Alo[4][2];
#pragma unroll
  for (int mt = 0; mt < 4; ++mt) {
    const int row = eBlock + w * 64 + mt * 16 + n;
    const u32x4* hp = reinterpret_cast<const u32x4*>(h2g + (size_t)row * 64);
#pragma unroll
    for (int s = 0; s < 2; ++s) {
      const u32x4 qa = hp[s * 8 + g * 2];
      const u32x4 qb = hp[s * 8 + g * 2 + 1];
      u32x4 hv, lv;
      hv[0] = (qa[0] & 0xffffu) | (qa[1] << 16);
      hv[1] = (qa[2] & 0xffffu) | (qa[3] << 16);
      hv[2] = (qb[0] & 0xffffu) | (qb[1] << 16);
      hv[3] = (qb[2] & 0xffffu) | (qb[3] << 16);
      lv[0] = (qa[0] >> 16) | (qa[1] & 0xffff0000u);
      lv[1] = (qa[2] >> 16) | (qa[3] & 0xffff0000u);
      lv[2] = (qb[0] >> 16) | (qb[1] & 0xffff0000u);
      lv[3] = (qb[2] >> 16) | (qb[3] & 0xffff0000u);
      Ahi[mt][s] = __builtin_bit_cast(bf16x8, hv);
      Alo[mt][s] = __builtin_bit_cast(bf16x8, lv);
    }
  }

  f32x4 shsv[4]; i32x4 dstv[4];
#pragma unroll
  for (int mt = 0; mt < 4; ++mt) {
    shsv[mt] = *reinterpret_cast<const f32x4*>(&shsT[w][mt * 16 + g * 4]);
    dstv[mt] = *reinterpret_cast<const i32x4*>(&dstT[w][mt * 16 + g * 4]);
  }

  const u32x4* bp4 = reinterpret_cast<const u32x4*>(bpk);

#define TILE_ACC(jp_)                                                          \
  f32x4 acc[4];                                                                \
  {                                                                            \
    u32x4 bfr[6];                                                              \
    _Pragma("unroll")                                                          \
    for (int s = 0; s < 6; ++s) bfr[s] = bp4[((jp_) * 6 + s) * 64 + lane];     \
    _Pragma("unroll")                                                          \
    for (int mt = 0; mt < 4; ++mt) acc[mt] = (f32x4)(0.0f);                    \
    _Pragma("unroll")                                                          \
    for (int s = 0; s < 6; ++s) {                                              \
      const bf16x8 B = __builtin_bit_cast(bf16x8, bfr[s]);                     \
      _Pragma("unroll")                                                        \
      for (int mt = 0; mt < 4; ++mt) {                                         \
        const bf16x8 A = (s < 2) ? Ahi[mt][s]                                  \
                                 : (s < 4 ? Alo[mt][s - 2] : Ahi[mt][s - 4]);  \
        acc[mt] = __builtin_amdgcn_mfma_f32_16x16x32_bf16(A, B, acc[mt], 0, 0, 0); \
      }                                                                        \
    }                                                                          \
    const float bv = b2s[cjp_map(jp_) * 16 + n];                               \
    _Pragma("unroll")                                                          \
    for (int mt = 0; mt < 4; ++mt) acc[mt] = acc[mt] + bv;                     \
  }

  // ---- phase A: out0 (w1: coef xs*shs, w4: coef dot)
  f32x4 out0[4];
#pragma unroll
  for (int mt = 0; mt < 4; ++mt) out0[mt] = (f32x4)(0.0f);
#pragma unroll 4
  for (int jp = 0; jp < 16; ++jp) {
    TILE_ACC(jp);
#pragma unroll
    for (int mt = 0; mt < 4; ++mt) {
      const f32x4 xsv = *reinterpret_cast<const f32x4*>(&xsT[w][jp][mt * 16 + g * 4]);
      out0[mt] += acc[mt] * shsv[mt] * xsv;
    }
  }
#pragma unroll 4
  for (int jp = 16; jp < 24; ++jp) {
    TILE_ACC(jp);
#pragma unroll
    for (int mt = 0; mt < 4; ++mt) {
      const f32x4 dv = *reinterpret_cast<const f32x4*>(&dtT[w][jp - 16][mt * 16 + g * 4]);
      out0[mt] += acc[mt] * dv;
    }
  }
#pragma unroll
  for (int mt = 0; mt < 4; ++mt)
#pragma unroll
    for (int r = 0; r < 4; ++r)
      atomicAdd(&agg[(size_t)dstv[mt][r] * D_C + n], out0[mt][r] * A0_C);

  // ---- phase B: s2 (w2: coef xs, shv folded at finalize)
  f32x4 s2[4];
#pragma unroll
  for (int mt = 0; mt < 4; ++mt) s2[mt] = (f32x4)(0.0f);
#pragma unroll 4
  for (int jp = 24; jp < 32; ++jp) {
    TILE_ACC(jp);
    const int u0 = (jp - 24) * 2 + (n >> 3);
#pragma unroll
    for (int mt = 0; mt < 4; ++mt) {
      const f32x4 xsv = *reinterpret_cast<const f32x4*>(&xsT[w][u0][mt * 16 + g * 4]);
      s2[mt] += acc[mt] * xsv;
    }
  }

  // ---- phase C: s3[m] (w3: coef xv[u][m], shs folded at finalize)
  f32x4 s3[3][4];
#pragma unroll
  for (int m = 0; m < 3; ++m)
#pragma unroll
    for (int mt = 0; mt < 4; ++mt) s3[m][mt] = (f32x4)(0.0f);
#pragma unroll 2
  for (int jp = 32; jp < 36; ++jp) {
    TILE_ACC(jp);
    const int u0 = (jp - 32) * 2 + (n >> 3);
#pragma unroll
    for (int mt = 0; mt < 4; ++mt)
#pragma unroll
      for (int m = 0; m < 3; ++m) {
        const f32x4 xvv = *reinterpret_cast<const f32x4*>(&xvT[w][u0][m][mt * 16 + g * 4]);
        s3[m][mt] += acc[mt] * xvv;
      }
  }

  // ---- finalize out1: lanes n and n^8 hold the u-split halves -> combine
#pragma unroll
  for (int mt = 0; mt < 4; ++mt)
#pragma unroll
    for (int m = 0; m < 3; ++m) {
      const f32x4 shvv = *reinterpret_cast<const f32x4*>(&shvT[w][m][mt * 16 + g * 4]);
      const f32x4 o = (s2[mt] * shvv + s3[m][mt] * shsv[mt]) * A0_C;
#pragma unroll
      for (int r = 0; r < 4; ++r) {
        float v = o[r];
        v += __shfl_xor(v, 8, 64);
        if (n < 8)
          atomicAdd(&agg[(size_t)dstv[mt][r] * D_C + 16 + n * 3 + m], v);
      }
    }
#undef TILE_ACC
}

// -------------------------------------------- K3a: residual add + BN statistics
__global__ __launch_bounds__(256) void resid_stats_kernel(
    const float* __restrict__ agg, const float* __restrict__ na,
    float* __restrict__ outp, float* __restrict__ stats)
{
  const int nn = blockIdx.x * 256 + threadIdx.x;
  float v[40];
  if (nn < N_NODES_C) {
    const float* ap = agg + (size_t)nn * D_C;
    const float* np = na + (size_t)nn * D_C;
#pragma unroll
    for (int i = 0; i < 10; ++i) {
      const float4 a = ld4(ap + i * 4);
      const float4 b = ld4(np + i * 4);
      v[i * 4] = a.x + b.x; v[i * 4 + 1] = a.y + b.y;
      v[i * 4 + 2] = a.z + b.z; v[i * 4 + 3] = a.w + b.w;
    }
    float* op = outp + (size_t)nn * D_C;
#pragma unroll
    for (int i = 0; i < 10; ++i)
      st4(op + i * 4, v[i * 4], v[i * 4 + 1], v[i * 4 + 2], v[i * 4 + 3]);
  } else {
#pragma unroll
    for (int i = 0; i < 40; ++i) v[i] = 0.f;
  }
  float red[40];
#pragma unroll
  for (int c = 0; c < 16; ++c) { red[c] = v[c]; red[16 + c] = v[c] * v[c]; }
#pragma unroll
  for (int u = 0; u < 8; ++u) {
    const float a = v[16 + u * 3], b = v[16 + u * 3 + 1], c = v[16 + u * 3 + 2];
    red[32 + u] = a * a + b * b + c * c;
  }
#pragma unroll
  for (int i = 0; i < 40; ++i) {
    float x = red[i];
#pragma unroll
    for (int off = 32; off > 0; off >>= 1) x += __shfl_xor(x, off, 64);
    red[i] = x;
  }
  if ((threadIdx.x & 63) == 0) {
#pragma unroll
    for (int i = 0; i < 40; ++i) atomicAdd(stats + i, red[i]);
  }
}

// ------------------------------------------------------------ K3b: BN apply
__global__ __launch_bounds__(256) void bn_apply_kernel(
    float* __restrict__ outp, const float* __restrict__ stats,
    const float* __restrict__ gs, const float* __restrict__ bsv,
    const float* __restrict__ gv)
{
  __shared__ float A[16], B[16], AV[8];
  const int tid = threadIdx.x;
  if (tid < 16) {
    const float s = stats[tid], q = stats[16 + tid];
    const float mu = s * (1.f / 20000.f);
    const float var = q * (1.f / 20000.f) - mu * mu;
    const float a = rsqrtf(var + 1e-5f) * gs[tid];
    A[tid] = a;
    B[tid] = bsv[tid] - mu * a;
  } else if (tid < 24) {
    const int u = tid - 16;
    const float vn = stats[32 + u] * (1.f / (20000.f * 3.f));
    AV[u] = rsqrtf(vn + 1e-5f) * gv[u];
  }
  __syncthreads();
  const int nn = blockIdx.x * 256 + tid;
  if (nn < N_NODES_C) {
    float* op = outp + (size_t)nn * D_C;
    float v[40];
#pragma unroll
    for (int i = 0; i < 10; ++i) {
      const float4 t = ld4(op + i * 4);
      v[i * 4] = t.x; v[i * 4 + 1] = t.y; v[i * 4 + 2] = t.z; v[i * 4 + 3] = t.w;
    }
#pragma unroll
    for (int c = 0; c < 16; ++c) v[c] = v[c] * A[c] + B[c];
#pragma unroll
    for (int u = 0; u < 8; ++u) {
      const float a = AV[u];
      v[16 + u * 3] *= a; v[16 + u * 3 + 1] *= a; v[16 + u * 3 + 2] *= a;
    }
#pragma unroll
    for (int i = 0; i < 10; ++i)
      st4(op + i * 4, v[i * 4], v[i * 4 + 1], v[i * 4 + 2], v[i * 4 + 3]);
  }
}

// ---------------------------------------------------------------- launcher
extern "C" void kernel_launch(void* const* d_in, const int* in_sizes, int n_in,
                              void* d_out, int out_size, void* d_ws, size_t ws_size,
                              hipStream_t stream) {
  const float* node_attr = (const float*)d_in[0];
  const float* edge_attr = (const float*)d_in[1];
  const float* edge_sh   = (const float*)d_in[2];
  const float* fc1_w     = (const float*)d_in[3];
  const float* fc1_b     = (const float*)d_in[4];
  const float* fc2_w     = (const float*)d_in[5];
  const float* fc2_b     = (const float*)d_in[6];
  const float* gs        = (const float*)d_in[7];
  const float* bs        = (const float*)d_in[8];
  const float* gv        = (const float*)d_in[9];
  const int*   ei        = (const int*)d_in[10];
  float* out = (float*)d_out;

  char* ws = (char*)d_ws;
  uint32_t* h2   = (uint32_t*)(ws);                      // 320000*64*4 = 81,920,000
  float*    agg  = (float*)(ws + 81920000);              // 20000*40*4  =  3,200,000
  float*    stats= (float*)(ws + 81920000 + 3200000);    // 40*4
  uint32_t* bpk  = (uint32_t*)d_out;                     // 245,760 B scratch; d_out
                                                         // rewritten later by K3a/b

  hipMemsetAsync(agg, 0, 3200000 + 160, stream);
  pack_kernel<<<240, 256, 0, stream>>>(fc2_w, fc1_w, bpk);
  fc1_mfma_kernel<<<1250, 256, 0, stream>>>(edge_attr, bpk, fc1_b, h2);
  edge_mfma_kernel<<<1250, 256, 0, stream>>>(h2, bpk, fc2_b, node_attr, edge_sh, ei, agg);
  resid_stats_kernel<<<79, 256, 0, stream>>>(agg, node_attr, out, stats);
  bn_apply_kernel<<<79, 256, 0, stream>>>(out, stats, gs, bs, gv);
}